// Round 5
// baseline (564.804 us; speedup 1.0000x reference)
//
#include <hip/hip_runtime.h>
#include <hip/hip_bf16.h>

#define N_NODE 50000
#define N_EDGE 625000
#define FDIM 128
#define NB_SCAN 196   // ceil(50000/256)

typedef __bf16 bf16x8 __attribute__((ext_vector_type(8)));
typedef float floatx4 __attribute__((ext_vector_type(4)));

#define MT 64        // nodes per block
#define XS_LD 264    // x-tile row stride (bf16): 256 + 8 pad (row = 528 B, 16B-aligned)
#define H_LD 136     // h row stride (bf16): 128 + 8 pad

__device__ inline bf16x8 as_bf16x8(uint4 v) {
    union { uint4 u; bf16x8 b; } c; c.u = v; return c.b;
}

// ---------------- prep: W repack (blocks 0..31) + zero count (blocks 32..63) ----------------
// Wpack[tile][nt][lane] = uint4 of 8 bf16: W[k0 + (lane>>4)*8 + j][nt*16 + (lane&15)]
// tiles: 0..7 = W1 (K=256), 8..11 = W2, 12..15 = W3
__global__ __launch_bounds__(256) void prep_kernel(
    const float* __restrict__ W1, const float* __restrict__ W2,
    const float* __restrict__ W3, uint4* __restrict__ wp,
    int* __restrict__ count)
{
    if (blockIdx.x >= 32) {
        int idx = (blockIdx.x - 32) * 256 + threadIdx.x;   // 0..8191
        for (int i = idx; i < N_NODE; i += 8192) count[i] = 0;
        return;
    }
    int g = blockIdx.x * 256 + threadIdx.x;   // 0..8191
    int lane = g & 63;
    int nt = (g >> 6) & 7;
    int tile = g >> 9;
    const float* W; int k0;
    if (tile < 8)       { W = W1; k0 = tile * 32; }
    else if (tile < 12) { W = W2; k0 = (tile - 8) * 32; }
    else                { W = W3; k0 = (tile - 12) * 32; }
    int n = nt * 16 + (lane & 15);
    int kb = k0 + (lane >> 4) * 8;
    union { __bf16 b[8]; uint4 u; } p;
#pragma unroll
    for (int j = 0; j < 8; ++j) p.b[j] = (__bf16)W[(kb + j) * 128 + n];
    wp[g] = p.u;
}

// ---------------- CSR build ----------------
__global__ __launch_bounds__(256) void hist_kernel(
    const int* __restrict__ recv, int* __restrict__ count)
{
    int e = blockIdx.x * 256 + threadIdx.x;
    if (e < N_EDGE) atomicAdd(&count[recv[e]], 1);
}

__global__ __launch_bounds__(256) void scan1_kernel(
    const int* __restrict__ count, int* __restrict__ off, int* __restrict__ bsum)
{
    __shared__ int s[256];
    int t = threadIdx.x;
    int i = blockIdx.x * 256 + t;
    int v = (i < N_NODE) ? count[i] : 0;
    s[t] = v;
    __syncthreads();
    for (int d = 1; d < 256; d <<= 1) {
        int x = (t >= d) ? s[t - d] : 0;
        __syncthreads();
        s[t] += x;
        __syncthreads();
    }
    if (i < N_NODE) off[i] = s[t] - v;              // block-local exclusive
    if (t == 255) bsum[blockIdx.x] = s[255];        // block total
}

// add scanned block bases; emit final off AND a cursor copy off2 for fill
__global__ __launch_bounds__(256) void scan2_kernel(
    int* __restrict__ off, int* __restrict__ off2, const int* __restrict__ bsum)
{
    __shared__ int s[256];
    int t = threadIdx.x;
    int v = (t < NB_SCAN) ? bsum[t] : 0;
    s[t] = v;
    __syncthreads();
    for (int d = 1; d < 256; d <<= 1) {
        int x = (t >= d) ? s[t - d] : 0;
        __syncthreads();
        s[t] += x;
        __syncthreads();
    }
    int i = blockIdx.x * 256 + t;
    if (i < N_NODE) {
        int o = off[i] + s[blockIdx.x] - ((blockIdx.x < NB_SCAN) ? bsum[blockIdx.x] : 0);
        off[i] = o;
        off2[i] = o;
    }
    if (i == N_NODE) off[i] = N_EDGE;               // sentinel
}

__global__ __launch_bounds__(256) void fill_kernel(
    const int* __restrict__ recv, int* __restrict__ off2, int* __restrict__ eid)
{
    int e = blockIdx.x * 256 + threadIdx.x;
    if (e < N_EDGE) {
        int r = recv[e];
        int slot = atomicAdd(&off2[r], 1);
        eid[slot] = e;
    }
}

// ---------------- edge gather: one wave per node, 2 edges per pass ----------------
__global__ __launch_bounds__(256) void gather_kernel(
    const float4* __restrict__ ef4, const int* __restrict__ off,
    const int* __restrict__ eid, uint2* __restrict__ agg)
{
    int wave = threadIdx.x >> 6;
    int lane = threadIdx.x & 63;
    int node = blockIdx.x * 4 + wave;                // grid = 12500, exact
    int half = lane >> 5;                            // which edge of the pair
    int c = lane & 31;                               // float4 column
    float4 acc = {0.f, 0.f, 0.f, 0.f};
    int s0 = off[node], e0 = off[node + 1];
    for (int base = s0; base < e0; base += 64) {
        int cnt = e0 - base; if (cnt > 64) cnt = 64;
        int ids = (lane < cnt) ? eid[base + lane] : 0;   // 1 coalesced load, 64 ids
        int j = 0;
        for (; j + 8 <= cnt; j += 8) {                   // 8 edges: 4 indep 16B loads/lane
            int ea = __shfl(ids, j + half);
            int eb = __shfl(ids, j + 2 + half);
            int ec = __shfl(ids, j + 4 + half);
            int ed = __shfl(ids, j + 6 + half);
            float4 va = ef4[(long)ea * 32 + c];
            float4 vb = ef4[(long)eb * 32 + c];
            float4 vc = ef4[(long)ec * 32 + c];
            float4 vd = ef4[(long)ed * 32 + c];
            acc.x += va.x + vb.x + vc.x + vd.x;
            acc.y += va.y + vb.y + vc.y + vd.y;
            acc.z += va.z + vb.z + vc.z + vd.z;
            acc.w += va.w + vb.w + vc.w + vd.w;
        }
        if (j + 4 <= cnt) {                              // 4 edges: 2 indep loads
            int ea = __shfl(ids, j + half);
            int eb = __shfl(ids, j + 2 + half);
            float4 va = ef4[(long)ea * 32 + c];
            float4 vb = ef4[(long)eb * 32 + c];
            acc.x += va.x + vb.x; acc.y += va.y + vb.y;
            acc.z += va.z + vb.z; acc.w += va.w + vb.w;
            j += 4;
        }
        if (j + 2 <= cnt) {                              // 2 edges: 1 load
            int ea = __shfl(ids, j + half);
            float4 va = ef4[(long)ea * 32 + c];
            acc.x += va.x; acc.y += va.y; acc.z += va.z; acc.w += va.w;
            j += 2;
        }
        if (j + half < cnt) {                            // last odd edge (half 0 only)
            int ea = __shfl(ids, j + half);
            float4 va = ef4[(long)ea * 32 + c];
            acc.x += va.x; acc.y += va.y; acc.z += va.z; acc.w += va.w;
        }
    }
    // fold the two halves: lanes 0..31 get cols 4c..4c+3 complete
    acc.x += __shfl_xor(acc.x, 32);
    acc.y += __shfl_xor(acc.y, 32);
    acc.z += __shfl_xor(acc.z, 32);
    acc.w += __shfl_xor(acc.w, 32);
    if (half == 0) {
        union { __bf16 b[4]; uint2 u; } p;
        p.b[0] = (__bf16)acc.x; p.b[1] = (__bf16)acc.y;
        p.b[2] = (__bf16)acc.z; p.b[3] = (__bf16)acc.w;
        agg[(long)node * 32 + c] = p.u;              // 256 B coalesced row
    }
}

// ------------- MLP + LayerNorm + residual -------------
__global__ __launch_bounds__(256, 3) void mlp_kernel(
    const float* __restrict__ nodef, const int* __restrict__ agg32,
    const uint4* __restrict__ wp,
    const float* __restrict__ b1, const float* __restrict__ b2,
    const float* __restrict__ b3,
    const float* __restrict__ gamma, const float* __restrict__ beta,
    float* __restrict__ out)
{
    __shared__ __bf16 xs[MT * XS_LD];    // x = [node || agg], bf16 (33792 B)
    __shared__ __bf16 h1[MT * H_LD];     // 17408 B
    __bf16* h2 = xs;                     // reuse xs after GEMM1

    const int t = threadIdx.x;
    const int wave = t >> 6;
    const int lane = t & 63;
    const int quad = lane >> 4;
    const int l16 = lane & 15;
    const int w16 = wave << 4;
    const int q8 = quad << 3;
    const int node0 = blockIdx.x * MT;

    // ---- stage x-tile ----
    const float4* nf4 = (const float4*)nodef;
#pragma unroll
    for (int i = 0; i < 8; ++i) {
        int it = i * 256 + t;
        int row = it >> 5;
        int c4 = it & 31;
        int node = node0 + row;
        if (node >= N_NODE) node = N_NODE - 1;   // junk ok; masked at store
        float4 v = nf4[(long)node * 32 + c4];
        union { __bf16 b[4]; short4 s; } u;
        u.b[0] = (__bf16)v.x; u.b[1] = (__bf16)v.y;
        u.b[2] = (__bf16)v.z; u.b[3] = (__bf16)v.w;
        *(short4*)&xs[row * XS_LD + c4 * 4] = u.s;
    }
    const int4* ag4 = (const int4*)agg32;        // 16 int4 per agg row
#pragma unroll
    for (int i = 0; i < 4; ++i) {
        int it = i * 256 + t;
        int row = it >> 4;
        int c8 = it & 15;
        int node = node0 + row;
        if (node >= N_NODE) node = N_NODE - 1;
        int4 v = ag4[(long)node * 16 + c8];
        *(int4*)&xs[row * XS_LD + 128 + c8 * 8] = v;
    }

    floatx4 acc[8];
    const floatx4 zero = {0.f, 0.f, 0.f, 0.f};

    // A[64 x 32*nk] @ Wpack-tiles -> acc; B-frags from global (L1/L2), prefetch depth 2
    auto run_gemm = [&](const __bf16* A, int ldA, const uint4* __restrict__ wpt, int nk) {
#pragma unroll
        for (int nt = 0; nt < 8; ++nt) acc[nt] = zero;
        const __bf16* arow = A + (w16 + l16) * ldA + q8;
        bf16x8 a0 = *(const bf16x8*)arow;
        bf16x8 b0[8], b1v[8];
#pragma unroll
        for (int nt = 0; nt < 8; ++nt) b0[nt] = as_bf16x8(wpt[nt * 64 + lane]);
        bf16x8 a1;
        if (nk > 1) {
            a1 = *(const bf16x8*)(arow + 32);
#pragma unroll
            for (int nt = 0; nt < 8; ++nt) b1v[nt] = as_bf16x8(wpt[(8 + nt) * 64 + lane]);
        }
#pragma unroll 8
        for (int kc = 0; kc < nk; ++kc) {
            bf16x8 a2; bf16x8 b2v[8];
            if (kc + 2 < nk) {
                a2 = *(const bf16x8*)(arow + (kc + 2) * 32);
#pragma unroll
                for (int nt = 0; nt < 8; ++nt)
                    b2v[nt] = as_bf16x8(wpt[((kc + 2) * 8 + nt) * 64 + lane]);
            }
#pragma unroll
            for (int nt = 0; nt < 8; ++nt)
                acc[nt] = __builtin_amdgcn_mfma_f32_16x16x32_bf16(a0, b0[nt], acc[nt], 0, 0, 0);
            a0 = a1; a1 = a2;
#pragma unroll
            for (int nt = 0; nt < 8; ++nt) { b0[nt] = b1v[nt]; b1v[nt] = b2v[nt]; }
        }
    };

    auto epilogue_relu = [&](const float* __restrict__ bias, __bf16* H) {
#pragma unroll
        for (int nt = 0; nt < 8; ++nt) {
            int col = nt * 16 + l16;
            float bv = bias[col];
#pragma unroll
            for (int r = 0; r < 4; ++r) {
                float v = acc[nt][r] + bv;
                v = v > 0.f ? v : 0.f;
                H[(w16 + quad * 4 + r) * H_LD + col] = (__bf16)v;
            }
        }
    };

    __syncthreads();                         // xs staged
    run_gemm(xs, XS_LD, wp, 8);              // GEMM1: K = 256
    epilogue_relu(b1, h1);
    __syncthreads();                         // h1 visible; xs reads done
    run_gemm(h1, H_LD, wp + 8 * 8 * 64, 4);  // GEMM2: K = 128
    epilogue_relu(b2, h2);                   // h2 = xs (safe: all waves past GEMM1)
    __syncthreads();                         // h2 visible
    run_gemm(h2, H_LD, wp + 12 * 8 * 64, 4); // GEMM3: K = 128

    // ---- final: +b3, LayerNorm, gamma/beta, +residual ----
    float vout[8][4];
    float sum[4] = {0.f, 0.f, 0.f, 0.f};
    float sq[4]  = {0.f, 0.f, 0.f, 0.f};
#pragma unroll
    for (int nt = 0; nt < 8; ++nt) {
        int col = nt * 16 + l16;
        float bv = b3[col];
#pragma unroll
        for (int r = 0; r < 4; ++r) {
            float v = acc[nt][r] + bv;
            vout[nt][r] = v;
            sum[r] += v;
            sq[r] += v * v;
        }
    }
#pragma unroll
    for (int r = 0; r < 4; ++r) {
#pragma unroll
        for (int offs = 1; offs < 16; offs <<= 1) {
            sum[r] += __shfl_xor(sum[r], offs);
            sq[r]  += __shfl_xor(sq[r], offs);
        }
    }
    float mu[4], rs[4];
#pragma unroll
    for (int r = 0; r < 4; ++r) {
        mu[r] = sum[r] * (1.f / 128.f);
        float var = sq[r] * (1.f / 128.f) - mu[r] * mu[r];
        rs[r] = rsqrtf(var + 1e-5f);
    }
#pragma unroll
    for (int nt = 0; nt < 8; ++nt) {
        int col = nt * 16 + l16;
        float g = gamma[col], be = beta[col];
#pragma unroll
        for (int r = 0; r < 4; ++r) {
            int row = w16 + quad * 4 + r;
            int node = node0 + row;
            if (node < N_NODE) {
                long o = (long)node * 128 + col;
                out[o] = (vout[nt][r] - mu[r]) * rs[r] * g + be + nodef[o];
            }
        }
    }
}

extern "C" void kernel_launch(void* const* d_in, const int* in_sizes, int n_in,
                              void* d_out, int out_size, void* d_ws, size_t ws_size,
                              hipStream_t stream)
{
    const float* nodef = (const float*)d_in[0];
    const int*   em    = (const int*)d_in[1];
    const float* ef    = (const float*)d_in[2];
    const float* W1    = (const float*)d_in[3];
    const float* b1    = (const float*)d_in[4];
    const float* W2    = (const float*)d_in[5];
    const float* b2    = (const float*)d_in[6];
    const float* W3    = (const float*)d_in[7];
    const float* b3    = (const float*)d_in[8];
    const float* gamma = (const float*)d_in[9];
    const float* beta  = (const float*)d_in[10];
    float* out = (float*)d_out;

    // workspace layout (ints)
    int* count = (int*)d_ws;             // 50048
    int* off   = count + 50048;          // 50048 (incl sentinel)
    int* off2  = off + 50048;            // 50048 (fill cursor)
    int* bsum  = off2 + 50048;           // 256
    int* eid   = bsum + 256;             // 625024
    int* agg32 = eid + 625024;           // 50000*64 ints (bf16x2) = 12.8 MB
    uint4* wp  = (uint4*)(agg32 + 3200000);  // 8192 uint4 = 128 KB (byte offset %16 == 0)

    const int* recv = em + N_EDGE;       // edge_matrix row 1 = receivers

    prep_kernel<<<64, 256, 0, stream>>>(W1, W2, W3, wp, count);

    int eblocks = (N_EDGE + 255) / 256;  // 2442
    hist_kernel<<<eblocks, 256, 0, stream>>>(recv, count);
    scan1_kernel<<<NB_SCAN, 256, 0, stream>>>(count, off, bsum);
    scan2_kernel<<<NB_SCAN, 256, 0, stream>>>(off, off2, bsum);
    fill_kernel<<<eblocks, 256, 0, stream>>>(recv, off2, eid);
    gather_kernel<<<N_NODE / 4, 256, 0, stream>>>((const float4*)ef, off, eid, (uint2*)agg32);

    int mblocks = (N_NODE + MT - 1) / MT;   // 782
    mlp_kernel<<<mblocks, 256, 0, stream>>>(nodef, agg32, wp, b1, b2, b3,
                                            gamma, beta, out);
}